// Round 2
// baseline (144.724 us; speedup 1.0000x reference)
//
#include <hip/hip_runtime.h>

// LatticeFilter: step-up (Levinson-Durbin) recursion, rc -> LPC coeffs.
//   rc: (B=16, p=128, Tf=8192) fp32, k_i = 0.98*rc[b,i,t]
//   out: (B, Tf, p+1=129) fp32, a[...,0]=1
//
// R2 changes vs R1:
//  - block=64, __launch_bounds__(64,1): 512-reg/wave budget so the 129-float
//    state lives entirely in arch VGPRs (R1's (256,2) cap produced VGPR=100 +
//    AGPR/scratch shuttling -> 2x VALU instructions). Occupancy is grid-bound
//    at 8 waves/CU either way (131072 threads total).
//  - 16-deep rolling register prefetch of k: load for step m+16 issues at
//    step m, hiding L2/L3 latency off the recursion's critical path.
//  - chunked LDS transpose epilogue: 64x33 floats (8.4 KB, stride 33 ->
//    conflict-free both phases), scalar dword stores = 2 full cache lines
//    per wave64 instr, perfectly coalesced; LDS never limits blocks/CU.

#define NB   16
#define ORD  128
#define TF   8192
#define PD   16   // k prefetch distance (power of 2)

__global__ __launch_bounds__(64, 1)
void lpc_stepup_kernel(const float* __restrict__ rc, float* __restrict__ out) {
    const int tid = threadIdx.x;              // 0..63
    const int gid = blockIdx.x * 64 + tid;    // flattened (B*Tf) column index
    const int b = gid >> 13;                  // gid / TF
    const int t = gid & (TF - 1);             // gid % TF
    const float* rcp = rc + ((size_t)b * ORD) * TF + t;

    // rolling prefetch ring for reflection coefficients
    float kq[PD];
#pragma unroll
    for (int i = 0; i < PD; ++i) kq[i] = rcp[(size_t)i * TF];

    float a[ORD + 1];
    a[0] = 1.0f;

#pragma unroll
    for (int m = 1; m <= ORD; ++m) {
        const float k = 0.98f * kq[(m - 1) & (PD - 1)];
        if (m - 1 + PD < ORD)                 // static after unroll
            kq[(m - 1) & (PD - 1)] = rcp[(size_t)(m - 1 + PD) * TF];
#pragma unroll
        for (int j = 1; 2 * j < m; ++j) {     // tmp-swap: both read old values
            const float lo = a[j];
            const float hi = a[m - j];
            a[j]     = fmaf(k, hi, lo);
            a[m - j] = fmaf(k, lo, hi);
        }
        if ((m & 1) == 0) {                   // middle element self-update
            const float mid = a[m >> 1];
            a[m >> 1] = fmaf(k, mid, mid);
        }
        a[m] = k;                             // a[0] == 1 contributes k
    }

    // ---- epilogue: 4 column-chunks of 32 coeffs through LDS ----
    // write phase: lds[tid*33 + j] -> banks (tid+j)%32, 2-way alias = free
    // read phase:  lane e: r=e>>5,q=e&31 -> banks (r+q)%32, 2-way = free
    // store phase: 64 lanes write 2 rows x 32 consecutive dwords = exactly
    //              2 x 128B lines per instruction
    __shared__ float lds[64 * 33];
    float* outb = out + (size_t)blockIdx.x * 64 * (ORD + 1);

#pragma unroll
    for (int c = 0; c < 4; ++c) {
        __syncthreads();
#pragma unroll
        for (int j = 0; j < 32; ++j)
            lds[tid * 33 + j] = a[c * 32 + j];
        __syncthreads();
        for (int e = tid; e < 2048; e += 64) {
            const int r = e >> 5, q = e & 31;
            outb[r * (ORD + 1) + c * 32 + q] = lds[r * 33 + q];
        }
    }
    // tail column 128 (one scattered dword store per thread)
    outb[tid * (ORD + 1) + ORD] = a[ORD];
}

extern "C" void kernel_launch(void* const* d_in, const int* in_sizes, int n_in,
                              void* d_out, int out_size, void* d_ws, size_t ws_size,
                              hipStream_t stream) {
    // d_in[0] = excitation (dead in reference), d_in[1] = rc
    const float* rc = (const float*)d_in[1];
    float* out = (float*)d_out;
    dim3 grid((NB * TF) / 64);
    dim3 block(64);
    hipLaunchKernelGGL(lpc_stepup_kernel, grid, block, 0, stream, rc, out);
}

// Round 3
// 140.851 us; speedup vs baseline: 1.0275x; 1.0275x over previous
//
#include <hip/hip_runtime.h>

// LatticeFilter: step-up (Levinson-Durbin) recursion, rc -> LPC coeffs.
//   rc: (B=16, p=128, Tf=8192) fp32, k_i = 0.98*rc[b,i,t]
//   out: (B, Tf, p+1=129) fp32, a[...,0]=1
//
// R3: the R1/R2 `#pragma unroll` chain silently failed (VGPR=104 is too few
// for a 129-float live array; insensitive to launch_bounds => a[] was in
// scratch, bouncing in L2/L3 where HBM counters can't see it). Replace the
// loops with compile-time template recursion: every a[] index is a template
// parameter, so SROA must scalarize the array into registers. Epilogue is
// R1's proven exactly-once float4 path (WRITE_SIZE was exactly 66,048 KB).

#define NB   16
#define ORD  128
#define TF   8192

// pair update j <-> m-j, both reading pre-step values (tmp-swap)
template<int M, int J>
struct PairUpd {
    static __device__ __forceinline__ void run(float (&a)[ORD + 1], float k) {
        const float lo = a[J];
        const float hi = a[M - J];
        a[J]     = fmaf(k, hi, lo);
        a[M - J] = fmaf(k, lo, hi);
        if constexpr (2 * (J + 1) < M) PairUpd<M, J + 1>::run(a, k);
    }
};

template<int M>
struct Step {
    static __device__ __forceinline__ void run(float (&a)[ORD + 1],
                                               const float* __restrict__ rcp) {
        const float k = 0.98f * rcp[(size_t)(M - 1) * TF];
        if constexpr (2 < M) PairUpd<M, 1>::run(a, k);
        if constexpr ((M & 1) == 0) {          // middle element self-update
            const float mid = a[M / 2];
            a[M / 2] = fmaf(k, mid, mid);
        }
        a[M] = k;                              // a[0] == 1 contributes k
        if constexpr (M < ORD) Step<M + 1>::run(a, rcp);
    }
};

__global__ __launch_bounds__(256, 2)
void lpc_stepup_kernel(const float* __restrict__ rc, float* __restrict__ out) {
    const int tid = threadIdx.x;
    const int gid = blockIdx.x * 256 + tid;   // flattened (B*Tf) column
    const int b = gid >> 13;                  // gid / TF
    const int t = gid & (TF - 1);             // gid % TF
    const float* rcp = rc + ((size_t)b * ORD) * TF + t;

    float a[ORD + 1];
    a[0] = 1.0f;
    Step<1>::run(a, rcp);                     // straight-line, fully scalarized

    // ---- epilogue: transpose 256 rows x 129 cols through LDS, 4 rounds ----
    // stage: bank stride 1 (129 mod 32 = 1) -> free 2-way wave64 aliasing
    // store: 2064 contiguous float4 per round -> every 128B line written whole
    __shared__ __align__(16) float lds[64 * (ORD + 1)];   // 33,024 B
    const int my_round = tid >> 6;            // wave index — uniform branch
    const int row      = tid & 63;
    float* out_block = out + (size_t)blockIdx.x * 256 * (ORD + 1);

    for (int r = 0; r < 4; ++r) {
        __syncthreads();
        if (my_round == r) {
#pragma unroll
            for (int j = 0; j <= ORD; ++j)
                lds[row * (ORD + 1) + j] = a[j];
        }
        __syncthreads();
        const float4* lds4 = (const float4*)lds;
        float4* out4 = (float4*)(out_block + (size_t)r * 64 * (ORD + 1));
        for (int e = tid; e < (64 * (ORD + 1)) / 4; e += 256)
            out4[e] = lds4[e];                // perfectly coalesced
    }
}

extern "C" void kernel_launch(void* const* d_in, const int* in_sizes, int n_in,
                              void* d_out, int out_size, void* d_ws, size_t ws_size,
                              hipStream_t stream) {
    // d_in[0] = excitation (dead in reference), d_in[1] = rc
    const float* rc = (const float*)d_in[1];
    float* out = (float*)d_out;
    dim3 grid((NB * TF) / 256);
    dim3 block(256);
    hipLaunchKernelGGL(lpc_stepup_kernel, grid, block, 0, stream, rc, out);
}